// Round 4
// baseline (501.868 us; speedup 1.0000x reference)
//
#include <hip/hip_runtime.h>
#include <stdint.h>

#define N 8192
#define D 256

typedef __attribute__((ext_vector_type(4))) float f32x4;
typedef __attribute__((ext_vector_type(8))) short bf16x8;

__device__ __forceinline__ unsigned short f2bf(float f) {
    unsigned u = __float_as_uint(f);
    u += 0x7fff + ((u >> 16) & 1);           // RNE
    return (unsigned short)(u >> 16);
}
__device__ __forceinline__ float leaky(float x) {
    return fmaxf(x, 0.f) + 0.2f * fminf(x, 0.f);
}
// CK-style block_sync_lds: LDS-ordering barrier that does NOT drain vmcnt,
// so register-destination global prefetches stay in flight across it.
__device__ __forceinline__ void sync_lds() {
    asm volatile("s_waitcnt lgkmcnt(0)\n\ts_barrier" ::: "memory");
}

// ---------------- K0: compress adj (fp32 0/1) + diagonal into bitmask ----------------
// mask[r][w] bit j  <=>  adj[r][w*32+j] > 0  ||  (w*32+j == r)
__global__ __launch_bounds__(256) void k0_compress(const float* __restrict__ adj,
                                                   unsigned int* __restrict__ mask) {
    const int idx = blockIdx.x * 256 + threadIdx.x;   // over N*N/32 words
    const int r = idx >> 8;                           // 256 words per row
    const int ww = idx & 255;
    const float* src = adj + ((size_t)idx << 5);      // 32 contiguous floats
    unsigned int bits = 0;
#pragma unroll
    for (int j = 0; j < 8; ++j) {
        float4 v = *(const float4*)(src + j * 4);
        bits |= (v.x > 0.f ? 1u : 0u) << (j * 4 + 0);
        bits |= (v.y > 0.f ? 1u : 0u) << (j * 4 + 1);
        bits |= (v.z > 0.f ? 1u : 0u) << (j * 4 + 2);
        bits |= (v.w > 0.f ? 1u : 0u) << (j * 4 + 3);
    }
    if ((r >> 5) == ww) bits |= 1u << (r & 31);       // diagonal
    mask[idx] = bits;
}

// ---------------- K1: Wh = x @ W (fp32), also write WhT bf16 [D][N] ----------------
#define K1_BM 16
__global__ __launch_bounds__(256) void k1_gemm(const float* __restrict__ x,
                                               const float* __restrict__ W,
                                               float* __restrict__ Wh,
                                               unsigned short* __restrict__ WhT) {
    __shared__ float xsT[32][20];   // [k][r]
    const int t = threadIdx.x;      // = output column
    const int r0 = blockIdx.x * K1_BM;
    float acc[K1_BM];
#pragma unroll
    for (int i = 0; i < K1_BM; ++i) acc[i] = 0.f;

    for (int k0 = 0; k0 < D; k0 += 32) {
        __syncthreads();
        if (t < 128) {
            int r = t >> 3, ks = (t & 7) * 4;
            float4 v = *(const float4*)(x + (size_t)(r0 + r) * D + k0 + ks);
            xsT[ks + 0][r] = v.x; xsT[ks + 1][r] = v.y;
            xsT[ks + 2][r] = v.z; xsT[ks + 3][r] = v.w;
        }
        __syncthreads();
#pragma unroll 8
        for (int kk = 0; kk < 32; ++kk) {
            float wv = W[(size_t)(k0 + kk) * D + t];
#pragma unroll
            for (int rc = 0; rc < K1_BM / 4; ++rc) {
                float4 xv = *(const float4*)&xsT[kk][rc * 4];
                acc[rc * 4 + 0] += xv.x * wv;
                acc[rc * 4 + 1] += xv.y * wv;
                acc[rc * 4 + 2] += xv.z * wv;
                acc[rc * 4 + 3] += xv.w * wv;
            }
        }
    }
#pragma unroll
    for (int r = 0; r < K1_BM; ++r) Wh[(size_t)(r0 + r) * D + t] = acc[r];
    unsigned short pk[K1_BM];
#pragma unroll
    for (int r = 0; r < K1_BM; ++r) pk[r] = f2bf(acc[r]);
    uint4* dst = (uint4*)(WhT + (size_t)t * N + r0);
    dst[0] = *(uint4*)&pk[0];
    dst[1] = *(uint4*)&pk[8];
}

// ---------------- K2: e_src / e_dst (wave per row) ----------------
__global__ __launch_bounds__(256) void k2_edot(const float* __restrict__ Wh,
                                               const float* __restrict__ a,
                                               float* __restrict__ e_src,
                                               float* __restrict__ e_dst) {
    const int wave = threadIdx.x >> 6, lane = threadIdx.x & 63;
    const int row = blockIdx.x * 4 + wave;
    float4 wv = *(const float4*)(Wh + (size_t)row * D + lane * 4);
    float4 as = *(const float4*)(a + lane * 4);
    float4 ad = *(const float4*)(a + D + lane * 4);
    float ps = wv.x * as.x + wv.y * as.y + wv.z * as.z + wv.w * as.w;
    float pd = wv.x * ad.x + wv.y * ad.y + wv.z * ad.z + wv.w * ad.w;
#pragma unroll
    for (int m = 1; m < 64; m <<= 1) {
        ps += __shfl_xor(ps, m);
        pd += __shfl_xor(pd, m);
    }
    if (lane == 0) { e_src[row] = ps; e_dst[row] = pd; }
}

// ---------------- K3: maxdst = max(e_dst) ----------------
__global__ __launch_bounds__(256) void k3_max(const float* __restrict__ e_dst,
                                              float* __restrict__ maxdst) {
    __shared__ float red[4];
    const int t = threadIdx.x;
    float m = -3.4e38f;
    for (int i = t; i < N; i += 256) m = fmaxf(m, e_dst[i]);
#pragma unroll
    for (int msk = 1; msk < 64; msk <<= 1) m = fmaxf(m, __shfl_xor(m, msk));
    if ((t & 63) == 0) red[t >> 6] = m;
    __syncthreads();
    if (t == 0) *maxdst = fmaxf(fmaxf(red[0], red[1]), fmaxf(red[2], red[3]));
}

// ---------------- K4: masked softmax + PV matmul (bitmask adj, j-split) ----------------
#define BM 64
#define BK 64
#define RB (N / BM)                 // 128 row-blocks
#define SPLITS 8                    // grid = RB*SPLITS = 1024
#define NITER ((N / SPLITS) / BK)   // 16
#define PSTRIDE 72                  // ushorts per P row (144 B)
__global__ __launch_bounds__(512, 4) void k4_main(const unsigned char* __restrict__ mask,
                                                  const unsigned short* __restrict__ WhT,
                                                  const float* __restrict__ e_src,
                                                  const float* __restrict__ e_dst,
                                                  const float* __restrict__ maxdst,
                                                  float* __restrict__ O_part,
                                                  float* __restrict__ l_part) {
    __shared__ unsigned short p_lds[2][BM][PSTRIDE];   // double-buffered P tile, 18.4 KB

    const int t = threadIdx.x;
    const int rb = blockIdx.x & (RB - 1);
    const int s  = blockIdx.x >> 7;          // RB = 128
    const int r0 = rb * BM;
    const int j0 = s * (N / SPLITS);

    // P-generation coords: 8 threads per row, 8 cols each
    const int pr = t >> 3;            // 0..63
    const int pcw = t & 7;            // byte lane within row slice
    const int pc = pcw * 8;           // 0..56
    const int gr = r0 + pr;

    const int w = t >> 6;             // wave 0..7 -> output cols w*32..w*32+31
    const int lane = t & 63;
    const int quad = lane >> 4, lo = lane & 15;

    const float md = *maxdst;
    const float es = e_src[gr];
    const float m = leaky(es + md);

    f32x4 acc[4][2];
#pragma unroll
    for (int mt = 0; mt < 4; ++mt)
#pragma unroll
        for (int nt = 0; nt < 2; ++nt)
            acc[mt][nt] = (f32x4){0.f, 0.f, 0.f, 0.f};
    float lsum = 0.f;

    // mask row slice: 128 B per (row, split); this thread's byte for iter `it`
    // is mrow[it*8] (pcw folded into base).
    const unsigned char* mrow = mask + (size_t)gr * (N / 8) + (j0 >> 3) + pcw;
    const float* ed_row = e_dst + j0 + pc;
    const unsigned short* wt_base = WhT + (size_t)(w * 32 + lo) * N + j0 + quad * 8;

    unsigned int mb;
    float4 edv0, edv1;
    bf16x8 bfr[2][2];                 // [ks2][nt]

    // ---- prologue: loads for tile 0 ----
    mb = mrow[0];
    edv0 = *(const float4*)(ed_row);
    edv1 = *(const float4*)(ed_row + 4);
#pragma unroll
    for (int ks2 = 0; ks2 < 2; ++ks2)
#pragma unroll
        for (int nt = 0; nt < 2; ++nt)
            bfr[ks2][nt] = *(const bf16x8*)(wt_base + (size_t)nt * (16 * N) + ks2 * 32);

    auto stage = [&](int buf) {
        float ev[8] = {edv0.x, edv0.y, edv0.z, edv0.w,
                       edv1.x, edv1.y, edv1.z, edv1.w};
        unsigned short pk[8];
#pragma unroll
        for (int jj = 0; jj < 8; ++jj) {
            float e = leaky(es + ev[jj]);
            float p = ((mb >> jj) & 1u) ? __expf(e - m) : 0.f;
            lsum += p;
            pk[jj] = f2bf(p);
        }
        *(uint4*)&p_lds[buf][pr][pc] = *(uint4*)pk;
    };

    // stage(0), then prefetch mask/ed for tile 1
    stage(0);
    mb = mrow[8];
    edv0 = *(const float4*)(ed_row + BK);
    edv1 = *(const float4*)(ed_row + BK + 4);
    sync_lds();

#pragma unroll 2
    for (int it = 0; it < NITER; ++it) {
        const int cb = it & 1, nb = cb ^ 1;

        // ---- MFMA on p_lds[cb] x bfr ----
#pragma unroll
        for (int ks2 = 0; ks2 < 2; ++ks2) {
            bf16x8 afr[4];
#pragma unroll
            for (int mt = 0; mt < 4; ++mt)
                afr[mt] = *(const bf16x8*)&p_lds[cb][mt * 16 + lo][ks2 * 32 + quad * 8];
#pragma unroll
            for (int nt = 0; nt < 2; ++nt)
#pragma unroll
                for (int mt = 0; mt < 4; ++mt)
                    acc[mt][nt] = __builtin_amdgcn_mfma_f32_16x16x32_bf16(
                        afr[mt], bfr[ks2][nt], acc[mt][nt], 0, 0, 0);
        }

        // ---- reissue B-fragment loads for it+1 ----
        {
            const int itn = (it + 1 < NITER) ? it + 1 : NITER - 1;
#pragma unroll
            for (int ks2 = 0; ks2 < 2; ++ks2)
#pragma unroll
                for (int nt = 0; nt < 2; ++nt)
                    bfr[ks2][nt] = *(const bf16x8*)(wt_base + (size_t)nt * (16 * N) +
                                                    itn * BK + ks2 * 32);
        }

        // ---- stage(it+1) into p_lds[nb], prefetch mask/ed for it+2 ----
        if (it + 1 < NITER) {
            stage(nb);
            const int itn2 = (it + 2 < NITER) ? it + 2 : NITER - 1;
            mb = mrow[itn2 * 8];
            edv0 = *(const float4*)(ed_row + itn2 * BK);
            edv1 = *(const float4*)(ed_row + itn2 * BK + 4);
        }
        sync_lds();
    }

    // ---- epilogue: reduce per-row partial l (8 threads per row), write partials ----
#pragma unroll
    for (int msk = 1; msk < 8; msk <<= 1) lsum += __shfl_xor(lsum, msk);
    if ((t & 7) == 0) l_part[(size_t)s * N + gr] = lsum;

#pragma unroll
    for (int mt = 0; mt < 4; ++mt) {
#pragma unroll
        for (int nt = 0; nt < 2; ++nt) {
            f32x4 v = acc[mt][nt];
            int col = w * 32 + nt * 16 + lo;
#pragma unroll
            for (int reg = 0; reg < 4; ++reg) {
                int row = mt * 16 + quad * 4 + reg;
                O_part[((size_t)s * N + r0 + row) * D + col] = v[reg];
            }
        }
    }
}

// ---------------- K5: reduce partials (float4), divide by l ----------------
__global__ __launch_bounds__(256) void k5_reduce(const float* __restrict__ O_part,
                                                 const float* __restrict__ l_part,
                                                 float* __restrict__ out) {
    const int idx = blockIdx.x * 256 + threadIdx.x;   // over N*D/4
    const int r = idx >> 6;                           // D/4 = 64 float4 per row
    float lsum = 0.f;
#pragma unroll
    for (int s = 0; s < SPLITS; ++s) lsum += l_part[(size_t)s * N + r];
    f32x4 o = (f32x4){0.f, 0.f, 0.f, 0.f};
#pragma unroll
    for (int s = 0; s < SPLITS; ++s)
        o += *(const f32x4*)(O_part + (size_t)s * N * D + (size_t)idx * 4);
    const float inv = 1.f / lsum;
    *(f32x4*)(out + (size_t)idx * 4) = o * inv;
}

// ---------------- launch ----------------
extern "C" void kernel_launch(void* const* d_in, const int* in_sizes, int n_in,
                              void* d_out, int out_size, void* d_ws, size_t ws_size,
                              hipStream_t stream) {
    const float* x   = (const float*)d_in[0];   // [N, D]
    const float* adj = (const float*)d_in[1];   // [N, N]
    const float* W   = (const float*)d_in[2];   // [D, D]
    const float* a   = (const float*)d_in[3];   // [2*D]
    float* out = (float*)d_out;

    // ws layout (~92 MB):
    char* ws = (char*)d_ws;
    float* Wh            = (float*)(ws);                         // 8 MB
    unsigned short* WhT  = (unsigned short*)(ws + 8388608);      // 4 MB
    float* e_src         = (float*)(ws + 12582912);              // 32 KB
    float* e_dst         = (float*)(ws + 12615680);              // 32 KB
    float* maxdst        = (float*)(ws + 12648448);              // 256 B
    float* l_part        = (float*)(ws + 12648704);              // 256 KB
    unsigned int* mask   = (unsigned int*)(ws + 13631488);       // 8 MB (N*N/8 bytes)
    float* O_part        = (float*)(ws + 25165824);              // 64 MB (SPLITS*N*D*4)

    k0_compress<<<N * N / 32 / 256, 256, 0, stream>>>(adj, mask);
    k1_gemm<<<N / K1_BM, 256, 0, stream>>>(x, W, Wh, WhT);
    k2_edot<<<N / 4, 256, 0, stream>>>(Wh, a, e_src, e_dst);
    k3_max<<<1, 256, 0, stream>>>(e_dst, maxdst);
    k4_main<<<RB * SPLITS, 512, 0, stream>>>((const unsigned char*)mask, WhT, e_src, e_dst,
                                             maxdst, O_part, l_part);
    k5_reduce<<<N * D / 4 / 256, 256, 0, stream>>>(O_part, l_part, out);
}

// Round 5
// 484.665 us; speedup vs baseline: 1.0355x; 1.0355x over previous
//
#include <hip/hip_runtime.h>
#include <stdint.h>

#define N 8192
#define D 256

typedef __attribute__((ext_vector_type(4))) float f32x4;
typedef __attribute__((ext_vector_type(8))) short bf16x8;

__device__ __forceinline__ unsigned short f2bf(float f) {
    unsigned u = __float_as_uint(f);
    u += 0x7fff + ((u >> 16) & 1);           // RNE
    return (unsigned short)(u >> 16);
}
__device__ __forceinline__ float leaky(float x) {
    return fmaxf(x, 0.f) + 0.2f * fminf(x, 0.f);
}
// CK-style block_sync_lds: LDS-ordering barrier that does NOT drain vmcnt,
// so register-destination global prefetches stay in flight across it.
__device__ __forceinline__ void sync_lds() {
    asm volatile("s_waitcnt lgkmcnt(0)\n\ts_barrier" ::: "memory");
}

// ---------------- K0: compress adj (fp32 0/1) + diagonal into bitmask ----------------
// Coalesced: lane reads one float4 (16 B/lane); 8-lane shfl-OR builds each u32 word.
__global__ __launch_bounds__(256) void k0_compress(const float* __restrict__ adj,
                                                   unsigned int* __restrict__ mask) {
    const size_t fbase = ((size_t)blockIdx.x * 256 + threadIdx.x) * 4;  // float index
    float4 v = *(const float4*)(adj + fbase);
    const int lane = threadIdx.x & 63;
    unsigned nib = (v.x > 0.f ? 1u : 0u) | (v.y > 0.f ? 2u : 0u) |
                   (v.z > 0.f ? 4u : 0u) | (v.w > 0.f ? 8u : 0u);
    unsigned word = nib << ((lane & 7) * 4);
    word |= __shfl_xor(word, 1);
    word |= __shfl_xor(word, 2);
    word |= __shfl_xor(word, 4);
    if ((lane & 7) == 0) {
        size_t widx = fbase >> 5;                 // word index; word covers 32 floats
        int r = (int)(widx >> 8);                 // 256 words per row
        int ww = (int)(widx & 255);
        if ((r >> 5) == ww) word |= 1u << (r & 31);   // diagonal
        mask[widx] = word;
    }
}

// ---------------- K1: Wh = x @ W (fp32), also write WhT bf16 [D][N] ----------------
#define K1_BM 8
__global__ __launch_bounds__(256) void k1_gemm(const float* __restrict__ x,
                                               const float* __restrict__ W,
                                               float* __restrict__ Wh,
                                               unsigned short* __restrict__ WhT) {
    __shared__ float xsT[32][12];   // [k][r]
    const int t = threadIdx.x;      // = output column
    const int r0 = blockIdx.x * K1_BM;
    float acc[K1_BM];
#pragma unroll
    for (int i = 0; i < K1_BM; ++i) acc[i] = 0.f;

    for (int k0 = 0; k0 < D; k0 += 32) {
        __syncthreads();
        if (t < 64) {
            int r = t >> 3, ks = (t & 7) * 4;
            float4 v = *(const float4*)(x + (size_t)(r0 + r) * D + k0 + ks);
            xsT[ks + 0][r] = v.x; xsT[ks + 1][r] = v.y;
            xsT[ks + 2][r] = v.z; xsT[ks + 3][r] = v.w;
        }
        __syncthreads();
#pragma unroll 8
        for (int kk = 0; kk < 32; ++kk) {
            float wv = W[(size_t)(k0 + kk) * D + t];
#pragma unroll
            for (int rc = 0; rc < K1_BM / 4; ++rc) {
                float4 xv = *(const float4*)&xsT[kk][rc * 4];
                acc[rc * 4 + 0] += xv.x * wv;
                acc[rc * 4 + 1] += xv.y * wv;
                acc[rc * 4 + 2] += xv.z * wv;
                acc[rc * 4 + 3] += xv.w * wv;
            }
        }
    }
#pragma unroll
    for (int r = 0; r < K1_BM; ++r) Wh[(size_t)(r0 + r) * D + t] = acc[r];
    unsigned short pk[K1_BM];
#pragma unroll
    for (int r = 0; r < K1_BM; ++r) pk[r] = f2bf(acc[r]);
    uint4* dst = (uint4*)(WhT + (size_t)t * N + r0);
    dst[0] = *(uint4*)&pk[0];
}

// ---------------- K2: e_src / e_dst (wave per row) ----------------
__global__ __launch_bounds__(256) void k2_edot(const float* __restrict__ Wh,
                                               const float* __restrict__ a,
                                               float* __restrict__ e_src,
                                               float* __restrict__ e_dst) {
    const int wave = threadIdx.x >> 6, lane = threadIdx.x & 63;
    const int row = blockIdx.x * 4 + wave;
    float4 wv = *(const float4*)(Wh + (size_t)row * D + lane * 4);
    float4 as = *(const float4*)(a + lane * 4);
    float4 ad = *(const float4*)(a + D + lane * 4);
    float ps = wv.x * as.x + wv.y * as.y + wv.z * as.z + wv.w * as.w;
    float pd = wv.x * ad.x + wv.y * ad.y + wv.z * ad.z + wv.w * ad.w;
#pragma unroll
    for (int m = 1; m < 64; m <<= 1) {
        ps += __shfl_xor(ps, m);
        pd += __shfl_xor(pd, m);
    }
    if (lane == 0) { e_src[row] = ps; e_dst[row] = pd; }
}

// ---------------- K3: maxdst = max(e_dst) ----------------
__global__ __launch_bounds__(256) void k3_max(const float* __restrict__ e_dst,
                                              float* __restrict__ maxdst) {
    __shared__ float red[4];
    const int t = threadIdx.x;
    float m = -3.4e38f;
    for (int i = t; i < N; i += 256) m = fmaxf(m, e_dst[i]);
#pragma unroll
    for (int msk = 1; msk < 64; msk <<= 1) m = fmaxf(m, __shfl_xor(m, msk));
    if ((t & 63) == 0) red[t >> 6] = m;
    __syncthreads();
    if (t == 0) *maxdst = fmaxf(fmaxf(red[0], red[1]), fmaxf(red[2], red[3]));
}

// ---------------- K4: masked softmax + PV matmul (bitmask adj, j-split) ----------------
#define BM 64
#define BK 64
#define RB (N / BM)                 // 128 row-blocks
#define SPLITS 8                    // grid = RB*SPLITS = 1024
#define NITER ((N / SPLITS) / BK)   // 16
#define PSTRIDE 72                  // ushorts per P row (144 B)
__global__ __launch_bounds__(512, 4) void k4_main(const unsigned char* __restrict__ mask,
                                                  const unsigned short* __restrict__ WhT,
                                                  const float* __restrict__ e_src,
                                                  const float* __restrict__ e_dst,
                                                  const float* __restrict__ maxdst,
                                                  float* __restrict__ O_part,
                                                  float* __restrict__ l_part) {
    __shared__ unsigned short p_lds[2][BM][PSTRIDE];   // double-buffered P tile, 18.4 KB

    const int t = threadIdx.x;
    const int rb = blockIdx.x & (RB - 1);
    const int s  = blockIdx.x >> 7;          // RB = 128
    const int r0 = rb * BM;
    const int j0 = s * (N / SPLITS);

    // P-generation coords: 8 threads per row, 8 cols each
    const int pr = t >> 3;            // 0..63
    const int pcw = t & 7;            // byte lane within row slice
    const int pc = pcw * 8;           // 0..56
    const int gr = r0 + pr;

    const int w = t >> 6;             // wave 0..7 -> output cols w*32..w*32+31
    const int lane = t & 63;
    const int quad = lane >> 4, lo = lane & 15;

    const float md = *maxdst;
    const float es = e_src[gr];
    const float m = leaky(es + md);

    f32x4 acc[4][2];
#pragma unroll
    for (int mt = 0; mt < 4; ++mt)
#pragma unroll
        for (int nt = 0; nt < 2; ++nt)
            acc[mt][nt] = (f32x4){0.f, 0.f, 0.f, 0.f};
    float lsum = 0.f;

    const unsigned char* mrow = mask + (size_t)gr * (N / 8) + (j0 >> 3) + pcw;
    const float* ed_row = e_dst + j0 + pc;
    const unsigned short* wt_base = WhT + (size_t)(w * 32 + lo) * N + j0 + quad * 8;

    unsigned int mb;
    float4 edv0, edv1;
    bf16x8 bfr[2][2];                 // [ks2][nt]

    // ---- prologue: loads for tile 0 ----
    mb = mrow[0];
    edv0 = *(const float4*)(ed_row);
    edv1 = *(const float4*)(ed_row + 4);
#pragma unroll
    for (int ks2 = 0; ks2 < 2; ++ks2)
#pragma unroll
        for (int nt = 0; nt < 2; ++nt)
            bfr[ks2][nt] = *(const bf16x8*)(wt_base + (size_t)nt * (16 * N) + ks2 * 32);

    auto stage = [&](int buf) {
        float ev[8] = {edv0.x, edv0.y, edv0.z, edv0.w,
                       edv1.x, edv1.y, edv1.z, edv1.w};
        unsigned short pk[8];
#pragma unroll
        for (int jj = 0; jj < 8; ++jj) {
            float e = leaky(es + ev[jj]);
            float p = ((mb >> jj) & 1u) ? __expf(e - m) : 0.f;
            lsum += p;
            pk[jj] = f2bf(p);
        }
        *(uint4*)&p_lds[buf][pr][pc] = *(uint4*)pk;
    };

    // stage(0), then prefetch mask/ed for tile 1
    stage(0);
    mb = mrow[8];
    edv0 = *(const float4*)(ed_row + BK);
    edv1 = *(const float4*)(ed_row + BK + 4);
    sync_lds();

#pragma unroll 2
    for (int it = 0; it < NITER; ++it) {
        const int cb = it & 1, nb = cb ^ 1;

        // ---- MFMA on p_lds[cb] x bfr ----
#pragma unroll
        for (int ks2 = 0; ks2 < 2; ++ks2) {
            bf16x8 afr[4];
#pragma unroll
            for (int mt = 0; mt < 4; ++mt)
                afr[mt] = *(const bf16x8*)&p_lds[cb][mt * 16 + lo][ks2 * 32 + quad * 8];
#pragma unroll
            for (int nt = 0; nt < 2; ++nt)
#pragma unroll
                for (int mt = 0; mt < 4; ++mt)
                    acc[mt][nt] = __builtin_amdgcn_mfma_f32_16x16x32_bf16(
                        afr[mt], bfr[ks2][nt], acc[mt][nt], 0, 0, 0);
        }

        // ---- reissue B-fragment loads for it+1 ----
        {
            const int itn = (it + 1 < NITER) ? it + 1 : NITER - 1;
#pragma unroll
            for (int ks2 = 0; ks2 < 2; ++ks2)
#pragma unroll
                for (int nt = 0; nt < 2; ++nt)
                    bfr[ks2][nt] = *(const bf16x8*)(wt_base + (size_t)nt * (16 * N) +
                                                    itn * BK + ks2 * 32);
        }

        // ---- stage(it+1) into p_lds[nb], prefetch mask/ed for it+2 ----
        if (it + 1 < NITER) {
            stage(nb);
            const int itn2 = (it + 2 < NITER) ? it + 2 : NITER - 1;
            mb = mrow[itn2 * 8];
            edv0 = *(const float4*)(ed_row + itn2 * BK);
            edv1 = *(const float4*)(ed_row + itn2 * BK + 4);
        }
        sync_lds();
    }

    // ---- epilogue: reduce per-row partial l (8 threads per row) ----
#pragma unroll
    for (int msk = 1; msk < 8; msk <<= 1) lsum += __shfl_xor(lsum, msk);
    if ((t & 7) == 0) l_part[(size_t)s * N + gr] = lsum;

    // ---- epilogue: O_part via LDS transpose -> fully-coalesced float4 stores ----
    // Reuse p_lds as a float staging buffer: 16 rows x 256 cols = 16 KB per chunk.
    float* obuf = (float*)p_lds;
#pragma unroll
    for (int mt = 0; mt < 4; ++mt) {
        __syncthreads();   // wait: prev chunk reads done / main-loop LDS reads done
#pragma unroll
        for (int nt = 0; nt < 2; ++nt) {
            f32x4 v = acc[mt][nt];
            int col = w * 32 + nt * 16 + lo;
#pragma unroll
            for (int reg = 0; reg < 4; ++reg)
                obuf[(quad * 4 + reg) * 256 + col] = v[reg];
        }
        __syncthreads();
        const int orow = t >> 5;            // 0..15
        const int ocol = (t & 31) * 8;      // 0..248
        f32x4 o0 = *(const f32x4*)&obuf[orow * 256 + ocol];
        f32x4 o1 = *(const f32x4*)&obuf[orow * 256 + ocol + 4];
        float* dst = O_part + ((size_t)s * N + r0 + mt * 16 + orow) * D + ocol;
        *(f32x4*)dst = o0;
        *(f32x4*)(dst + 4) = o1;
    }
}

// ---------------- K5: reduce partials (float4), divide by l ----------------
__global__ __launch_bounds__(256) void k5_reduce(const float* __restrict__ O_part,
                                                 const float* __restrict__ l_part,
                                                 float* __restrict__ out) {
    const int idx = blockIdx.x * 256 + threadIdx.x;   // over N*D/4
    const int r = idx >> 6;                           // D/4 = 64 float4 per row
    float lsum = 0.f;
#pragma unroll
    for (int s = 0; s < SPLITS; ++s) lsum += l_part[(size_t)s * N + r];
    f32x4 o = (f32x4){0.f, 0.f, 0.f, 0.f};
#pragma unroll
    for (int s = 0; s < SPLITS; ++s)
        o += *(const f32x4*)(O_part + (size_t)s * N * D + (size_t)idx * 4);
    const float inv = 1.f / lsum;
    *(f32x4*)(out + (size_t)idx * 4) = o * inv;
}

// ---------------- launch ----------------
extern "C" void kernel_launch(void* const* d_in, const int* in_sizes, int n_in,
                              void* d_out, int out_size, void* d_ws, size_t ws_size,
                              hipStream_t stream) {
    const float* x   = (const float*)d_in[0];   // [N, D]
    const float* adj = (const float*)d_in[1];   // [N, N]
    const float* W   = (const float*)d_in[2];   // [D, D]
    const float* a   = (const float*)d_in[3];   // [2*D]
    float* out = (float*)d_out;

    // ws layout (~92 MB):
    char* ws = (char*)d_ws;
    float* Wh            = (float*)(ws);                         // 8 MB
    unsigned short* WhT  = (unsigned short*)(ws + 8388608);      // 4 MB
    float* e_src         = (float*)(ws + 12582912);              // 32 KB
    float* e_dst         = (float*)(ws + 12615680);              // 32 KB
    float* maxdst        = (float*)(ws + 12648448);              // 256 B
    float* l_part        = (float*)(ws + 12648704);              // 256 KB
    unsigned int* mask   = (unsigned int*)(ws + 13631488);       // 8 MB (N*N/8 bytes)
    float* O_part        = (float*)(ws + 25165824);              // 64 MB (SPLITS*N*D*4)

    k0_compress<<<N * N / 4 / 256, 256, 0, stream>>>(adj, mask);
    k1_gemm<<<N / K1_BM, 256, 0, stream>>>(x, W, Wh, WhT);
    k2_edot<<<N / 4, 256, 0, stream>>>(Wh, a, e_src, e_dst);
    k3_max<<<1, 256, 0, stream>>>(e_dst, maxdst);
    k4_main<<<RB * SPLITS, 512, 0, stream>>>((const unsigned char*)mask, WhT, e_src, e_dst,
                                             maxdst, O_part, l_part);
    k5_reduce<<<N * D / 4 / 256, 256, 0, stream>>>(O_part, l_part, out);
}